// Round 6
// baseline (829.179 us; speedup 1.0000x reference)
//
#include <hip/hip_runtime.h>
#include <hip/hip_bf16.h>

#define DD 300
#define DP 320   // padded feature width

typedef unsigned short ushort_t;
typedef __attribute__((ext_vector_type(8))) short short8;
typedef __attribute__((ext_vector_type(4))) float f32x4;

__device__ __forceinline__ float b2f(ushort_t u) {
    unsigned x = ((unsigned)u) << 16;
    return __uint_as_float(x);
}
__device__ __forceinline__ ushort_t f2b(float f) {
    unsigned u = __float_as_uint(f);
    unsigned r = (u + 0x7FFFu + ((u >> 16) & 1u)) >> 16;
    return (ushort_t)r;
}

__device__ __forceinline__ void gload16(const void* g, void* l) {
    __builtin_amdgcn_global_load_lds((const __attribute__((address_space(1))) void*)g,
                                     (__attribute__((address_space(3))) void*)l, 16, 0, 0);
}

// ================= MFMA bf16 GEMM =================
// C[M][cols] = A[M][K](bf16) @ Bt^T ; Bt is [cols][K] bf16 pre-transposed/padded.
// BM=128, BK=64, BN=32*BNT, 512 threads = 8 waves (4 row x 2 col).
// SPLIT>0: cols >= SPLIT go to C1 (col-SPLIT), RANK3 applies to cols >= SPLIT.
// TRANSC: write C0[col*strideC + row] (for weight-combine products).
template<int BNT, int BIAS, int RELU, int RESID, int RANK3, int SPLIT, int TRANSC>
__launch_bounds__(512)
__global__ void gemm_mfma(const ushort_t* __restrict__ A, int strideA, int M, int K,
                          const ushort_t* __restrict__ Bt,
                          const float* __restrict__ bias,
                          const ushort_t* __restrict__ resid,
                          const float* __restrict__ X3,
                          const float* __restrict__ W3,
                          int NCOL,
                          ushort_t* __restrict__ C0,
                          ushort_t* __restrict__ C1,
                          int strideC)
{
    constexpr int BM = 128, BK = 64, BN = 32 * BNT;
    constexpr int CA = BM * BK * 2 / 1024;
    constexpr int CB = BN * BK * 2 / 1024;
    __shared__ ushort_t As[BM * BK];
    __shared__ ushort_t Bs[BN * BK];

    const int tid = threadIdx.x;
    const int lane = tid & 63, wid = tid >> 6;
    const int rowTile = blockIdx.y * BM;
    const int colTile = blockIdx.x * BN;
    const int wm = wid >> 1, wn = wid & 1;

    const int lrow = lane >> 3;
    const int l8b = (lane & 7) * 16;

    f32x4 acc[2][BNT];
    #pragma unroll
    for (int f = 0; f < 2; ++f)
        #pragma unroll
        for (int q = 0; q < BNT; ++q) {
            f32x4 z = {0.f, 0.f, 0.f, 0.f};
            acc[f][q] = z;
        }

    for (int k0 = 0; k0 < K; k0 += BK) {
        for (int c = wid; c < CA; c += 8) {
            int row = c * 8 + lrow;
            int colb = l8b ^ ((row & 7) << 4);
            int gr = rowTile + row; if (gr > M - 1) gr = M - 1;
            gload16(A + (size_t)gr * strideA + k0 + (colb >> 1), As + c * 512);
        }
        for (int c = wid; c < CB; c += 8) {
            int row = c * 8 + lrow;
            int colb = l8b ^ ((row & 7) << 4);
            gload16(Bt + (size_t)(colTile + row) * K + k0 + (colb >> 1), Bs + c * 512);
        }
        __syncthreads();

        #pragma unroll
        for (int ks = 0; ks < 2; ++ks) {
            const int kidx = ks * 32 + (lane >> 4) * 8;
            short8 af[2], bf[BNT];
            #pragma unroll
            for (int f = 0; f < 2; ++f) {
                int row = wm * 32 + f * 16 + (lane & 15);
                int phys = (row * 128 + kidx * 2) ^ ((row & 7) << 4);
                af[f] = *(const short8*)((const char*)As + phys);
            }
            #pragma unroll
            for (int q = 0; q < BNT; ++q) {
                int row = wn * 16 * BNT + q * 16 + (lane & 15);
                int phys = (row * 128 + kidx * 2) ^ ((row & 7) << 4);
                bf[q] = *(const short8*)((const char*)Bs + phys);
            }
            #pragma unroll
            for (int f = 0; f < 2; ++f)
                #pragma unroll
                for (int q = 0; q < BNT; ++q)
                    acc[f][q] = __builtin_amdgcn_mfma_f32_16x16x32_bf16(af[f], bf[q], acc[f][q], 0, 0, 0);
        }
        __syncthreads();
    }

    #pragma unroll
    for (int f = 0; f < 2; ++f) {
        #pragma unroll
        for (int r = 0; r < 4; ++r) {
            int row = rowTile + wm * 32 + f * 16 + (lane >> 4) * 4 + r;
            if (row >= M) continue;
            #pragma unroll
            for (int q = 0; q < BNT; ++q) {
                int col = colTile + wn * 16 * BNT + q * 16 + (lane & 15);
                float v = acc[f][q][r];
                if (TRANSC) {
                    C0[(size_t)col * strideC + row] = f2b(v);
                } else {
                    if (BIAS) v += bias[col];
                    if (RANK3) {
                        int c = col - SPLIT;
                        if (c >= 0 && c < NCOL)
                            v += X3[row * 3 + 0] * W3[c]
                               + X3[row * 3 + 1] * W3[NCOL + c]
                               + X3[row * 3 + 2] * W3[2 * NCOL + c];
                    }
                    if (RESID) v += b2f(resid[(size_t)row * strideC + col]);
                    if (RELU) v = fmaxf(v, 0.f);
                    if (SPLIT > 0 && col >= SPLIT)
                        C1[(size_t)row * strideC + (col - SPLIT)] = f2b(v);
                    else
                        C0[(size_t)row * strideC + col] = f2b(v);
                }
            }
        }
    }
}

// ============ single prep kernel: all weight transposes/pads ============
__global__ void prep(const float* __restrict__ pW2, const float* __restrict__ pW3,
                     const float* __restrict__ hW, const float* __restrict__ fW,
                     const float* __restrict__ gW, const float* __restrict__ gb,
                     const float* __restrict__ lW, const float* __restrict__ lb,
                     ushort_t* __restrict__ WU, ushort_t* __restrict__ WG,
                     ushort_t* __restrict__ Bt12, ushort_t* __restrict__ Bt23,
                     ushort_t* __restrict__ WL3, ushort_t* __restrict__ LWa0,
                     ushort_t* __restrict__ LWa1, ushort_t* __restrict__ pW3a,
                     ushort_t* __restrict__ Bt01, ushort_t* __restrict__ W2,
                     float* __restrict__ bG, float* __restrict__ bL3)
{
    const int SZ = DP * DP;
    int idx = blockIdx.x * 256 + threadIdx.x;
    // 1. WU[i][n][k]: n<300 -> fWh^T, n in 300..302 -> hW^T (delta cols)
    if (idx < 3 * SZ) {
        int i = idx / SZ, r = idx - i * SZ, n = r / DP, k = r - n * DP;
        float v = 0.f;
        if (k < DD) {
            if (n < DD) v = fW[i * 90900 + (3 + k) * DD + n];
            else if (n < DD + 3) v = hW[i * 900 + k * 3 + (n - DD)];
        }
        WU[idx] = f2b(v); return;
    }
    idx -= 3 * SZ;
    // 2. WG: gW^T padded
    if (idx < 3 * SZ) {
        int i = idx / SZ, r = idx - i * SZ, n = r / DP, k = r - n * DP;
        WG[idx] = f2b((n < DD && k < DD) ? gW[i * 90000 + k * DD + n] : 0.f); return;
    }
    idx -= 3 * SZ;
    // 3. Bt12 rows 0-319 = lW0^T
    if (idx < SZ) {
        int n = idx / DP, k = idx - n * DP;
        Bt12[idx] = f2b((n < DD && k < DD) ? lW[k * DD + n] : 0.f); return;
    }
    idx -= SZ;
    // 4. Bt23 rows 0-319 = lW1^T
    if (idx < SZ) {
        int n = idx / DP, k = idx - n * DP;
        Bt23[idx] = f2b((n < DD && k < DD) ? lW[90000 + k * DD + n] : 0.f); return;
    }
    idx -= SZ;
    // 5. WL3 = lW2^T
    if (idx < SZ) {
        int n = idx / DP, k = idx - n * DP;
        WL3[idx] = f2b((n < DD && k < DD) ? lW[180000 + k * DD + n] : 0.f); return;
    }
    idx -= SZ;
    // 6. LWa0 = lW0 row-major padded (A-format)
    if (idx < SZ) {
        int j = idx / DP, k = idx - j * DP;
        LWa0[idx] = f2b((j < DD && k < DD) ? lW[j * DD + k] : 0.f); return;
    }
    idx -= SZ;
    // 7. LWa1
    if (idx < SZ) {
        int j = idx / DP, k = idx - j * DP;
        LWa1[idx] = f2b((j < DD && k < DD) ? lW[90000 + j * DD + k] : 0.f); return;
    }
    idx -= SZ;
    // 8. pW3a = pW3 row-major [128][320] (A-format)
    if (idx < 128 * DP) {
        int j = idx / DP, k = idx - j * DP;
        pW3a[idx] = f2b((k < DD) ? pW3[j * DD + k] : 0.f); return;
    }
    idx -= 128 * DP;
    // 9. Bt01 rows 0-319 = pW3^T ([320][128])
    if (idx < DP * 128) {
        int n = idx >> 7, k = idx & 127;
        Bt01[idx] = f2b((n < DD) ? pW3[k * DD + n] : 0.f); return;
    }
    idx -= DP * 128;
    // 10. W2 = pW2^T [128][64]
    if (idx < 128 * 64) {
        int n = idx >> 6, k = idx & 63;
        W2[idx] = f2b(pW2[k * 128 + n]); return;
    }
    idx -= 128 * 64;
    // 11. bG padded f32
    if (idx < 3 * DP) {
        int i = idx / DP, n = idx - i * DP;
        bG[idx] = (n < DD) ? gb[i * DD + n] : 0.f; return;
    }
    idx -= 3 * DP;
    // 12. bL3 padded f32
    if (idx < DP) {
        bL3[idx] = (idx < DD) ? lb[2 * DD + idx] : 0.f; return;
    }
}

// ============ combined boundary biases ============
// boundary b: cols 0-319 = prev-linear bias (pb3 / lb0 / lb1) padded;
// cols 320-639: n=col-320: sum_k src[k]*WU_b[n][k] (+hb_b for delta cols)
__global__ void biascomb(const float* __restrict__ pb3, const float* __restrict__ lb,
                         const float* __restrict__ hb, const ushort_t* __restrict__ WU,
                         float* __restrict__ bC01, float* __restrict__ bC12,
                         float* __restrict__ bC23)
{
    int t = blockIdx.x * 256 + threadIdx.x;
    if (t >= 3 * 640) return;
    int b = t / 640, col = t - b * 640;
    const float* src = (b == 0) ? pb3 : lb + (b - 1) * DD;
    float* out = (b == 0) ? bC01 : (b == 1) ? bC12 : bC23;
    if (col < DP) {
        out[col] = (col < DD) ? src[col] : 0.f;
    } else {
        int n = col - DP;
        const ushort_t* w = WU + (size_t)b * DP * DP + (size_t)n * DP;
        float s = 0.f;
        for (int k = 0; k < DD; ++k) s += src[k] * b2f(w[k]);
        if (n >= DD && n < DD + 3) s += hb[b * 3 + (n - DD)];
        out[col] = s;
    }
}

// ============ embed layer 1: h1 = relu(x @ pW1 + pb1), K=3 ============
__global__ void embed1(const float* __restrict__ x, const float* __restrict__ W,
                       const float* __restrict__ b, ushort_t* __restrict__ h1, int M)
{
    int idx = blockIdx.x * 256 + threadIdx.x;
    if (idx >= M * 64) return;
    int n = idx >> 6, c = idx & 63;
    const float* xr = x + n * 3;
    float v = xr[0] * W[c] + xr[1] * W[64 + c] + xr[2] * W[128 + c] + b[c];
    h1[idx] = f2b(fmaxf(v, 0.f));
}

// ============ CSR build ============
__global__ void hist_kernel(const int* __restrict__ dst, int* __restrict__ cnt, int E)
{
    int e = blockIdx.x * 256 + threadIdx.x;
    if (e < E) atomicAdd(&cnt[dst[e]], 1);
}
__global__ void scan1(const int* __restrict__ cnt, int* __restrict__ bsum, int N)
{
    __shared__ int s[256];
    int t = threadIdx.x;
    int i = blockIdx.x * 256 + t;
    s[t] = (i < N) ? cnt[i] : 0;
    __syncthreads();
    for (int o = 128; o > 0; o >>= 1) { if (t < o) s[t] += s[t + o]; __syncthreads(); }
    if (t == 0) bsum[blockIdx.x] = s[0];
}
__global__ void scan2(int* __restrict__ bsum, int nb)
{
    __shared__ int s[256];
    int t = threadIdx.x;
    int v = (t < nb) ? bsum[t] : 0;
    s[t] = v; __syncthreads();
    for (int o = 1; o < 256; o <<= 1) {
        int x = (t >= o) ? s[t - o] : 0;
        __syncthreads();
        s[t] += x;
        __syncthreads();
    }
    if (t < nb) bsum[t] = s[t] - v;
}
__global__ void scan3(const int* __restrict__ cnt, const int* __restrict__ bsumx,
                      int* __restrict__ off, int* __restrict__ cursor, int N)
{
    __shared__ int s[256];
    int t = threadIdx.x;
    int i = blockIdx.x * 256 + t;
    int v = (i < N) ? cnt[i] : 0;
    s[t] = v; __syncthreads();
    for (int o = 1; o < 256; o <<= 1) {
        int x = (t >= o) ? s[t - o] : 0;
        __syncthreads();
        s[t] += x;
        __syncthreads();
    }
    int excl = s[t] - v + bsumx[blockIdx.x];
    if (i <= N) {
        off[i] = excl;
        if (i < N) cursor[i] = excl;
    }
}
__global__ void scatter_kernel(const int* __restrict__ src, const int* __restrict__ dst,
                               int* __restrict__ cursor, int* __restrict__ csr, int E)
{
    int e = blockIdx.x * 256 + threadIdx.x;
    if (e < E) {
        int p = atomicAdd(&cursor[dst[e]], 1);
        csr[p] = src[e];
    }
}

// ============ segment max over CSR ============
// All 64 lanes active, scalar coalesced 2B loads; 8/4/1 unroll cascade
// -> up to 40 independent cache lines in flight per wave.
__global__ void segmax(const ushort_t* __restrict__ u, const int* __restrict__ off,
                       const int* __restrict__ csr,
                       const float* __restrict__ x, const float* __restrict__ fWp,
                       const float* __restrict__ fb, ushort_t* __restrict__ agg, int Nn)
{
    int n = blockIdx.x * 4 + (threadIdx.x >> 6);
    int lane = threadIdx.x & 63;
    if (n >= Nn) return;
    const int e0 = off[n], e1 = off[n + 1];

    const ushort_t* un = u + (size_t)n * DP;
    float d0 = b2f(un[300]) - x[n * 3 + 0];
    float d1 = b2f(un[301]) - x[n * 3 + 1];
    float d2 = b2f(un[302]) - x[n * 3 + 2];

    float m[5];
    #pragma unroll
    for (int j = 0; j < 5; ++j) m[j] = -INFINITY;

    int e = e0;
    for (; e + 7 < e1; e += 8) {
        int s[8];
        #pragma unroll
        for (int q = 0; q < 8; ++q) s[q] = csr[e + q];
        #pragma unroll
        for (int q = 0; q < 8; ++q) {
            const ushort_t* r = u + (size_t)s[q] * DP + lane;
            #pragma unroll
            for (int j = 0; j < 5; ++j) m[j] = fmaxf(m[j], b2f(r[64 * j]));
        }
    }
    for (; e + 3 < e1; e += 4) {
        int s[4];
        #pragma unroll
        for (int q = 0; q < 4; ++q) s[q] = csr[e + q];
        #pragma unroll
        for (int q = 0; q < 4; ++q) {
            const ushort_t* r = u + (size_t)s[q] * DP + lane;
            #pragma unroll
            for (int j = 0; j < 5; ++j) m[j] = fmaxf(m[j], b2f(r[64 * j]));
        }
    }
    for (; e < e1; ++e) {
        const ushort_t* r = u + (size_t)csr[e] * DP + lane;
        #pragma unroll
        for (int j = 0; j < 5; ++j) m[j] = fmaxf(m[j], b2f(r[64 * j]));
    }

    #pragma unroll
    for (int j = 0; j < 5; ++j) {
        int col = lane + 64 * j;
        float o = 0.f;
        if (e1 > e0 && col < DD)
            o = m[j] + fb[col] + d0 * fWp[col] + d1 * fWp[DD + col] + d2 * fWp[2 * DD + col];
        agg[(size_t)n * DP + col] = f2b(o);
    }
}

// ============ global mean pool (bf16 h) ============
__global__ void pool_kernel(const ushort_t* __restrict__ h, const int* __restrict__ batch,
                            float* __restrict__ sums, float* __restrict__ cnts,
                            int Nn, int npb)
{
    int c = threadIdx.x;
    int n0 = blockIdx.x * npb;
    int n1 = min(n0 + npb, Nn);
    if (n0 >= n1) return;
    if (c < DD) {
        float run = 0.f;
        int g = batch[n0];
        for (int n = n0; n < n1; ++n) {
            int gn = batch[n];
            if (gn != g) { atomicAdd(&sums[g * DD + c], run); run = 0.f; g = gn; }
            run += b2f(h[(size_t)n * DP + c]);
        }
        atomicAdd(&sums[g * DD + c], run);
    } else if (c == DD) {
        float run = 0.f;
        int g = batch[n0];
        for (int n = n0; n < n1; ++n) {
            int gn = batch[n];
            if (gn != g) { atomicAdd(&cnts[g], run); run = 0.f; g = gn; }
            run += 1.f;
        }
        atomicAdd(&cnts[g], run);
    }
}

// ============ head: mean -> logits -> log_softmax ============
__global__ void head_kernel(const float* __restrict__ sums, const float* __restrict__ cnts,
                            const float* __restrict__ dW, const float* __restrict__ db,
                            float* __restrict__ out)
{
    __shared__ float mean[32][DD];
    __shared__ float logits[32][40];
    int tid = threadIdx.x;
    for (int i = tid; i < 32 * DD; i += 256) {
        int g = i / DD;
        mean[g][i - g * DD] = sums[i] / fmaxf(cnts[g], 1.f);
    }
    __syncthreads();
    for (int o = tid; o < 32 * 40; o += 256) {
        int g = o / 40, cls = o - g * 40;
        float acc = db[cls];
        for (int k = 0; k < DD; ++k) acc += mean[g][k] * dW[k * 40 + cls];
        logits[g][cls] = acc;
    }
    __syncthreads();
    if (tid < 32) {
        float mx = -INFINITY;
        #pragma unroll
        for (int j = 0; j < 40; ++j) mx = fmaxf(mx, logits[tid][j]);
        float se = 0.f;
        for (int j = 0; j < 40; ++j) se += expf(logits[tid][j] - mx);
        float lse = mx + logf(se);
        for (int j = 0; j < 40; ++j) out[tid * 40 + j] = logits[tid][j] - lse;
    }
}

extern "C" void kernel_launch(void* const* d_in, const int* in_sizes, int n_in,
                              void* d_out, int out_size, void* d_ws, size_t ws_size,
                              hipStream_t stream)
{
    const float* x     = (const float*)d_in[0];
    const int*   ei    = (const int*)d_in[1];
    const int*   batch = (const int*)d_in[2];
    const float* pW1   = (const float*)d_in[3];
    const float* pb1   = (const float*)d_in[4];
    const float* pW2   = (const float*)d_in[5];
    const float* pb2   = (const float*)d_in[6];
    const float* pW3   = (const float*)d_in[7];
    const float* pb3   = (const float*)d_in[8];
    const float* hW    = (const float*)d_in[9];
    const float* hb    = (const float*)d_in[10];
    const float* fW    = (const float*)d_in[11];
    const float* fb    = (const float*)d_in[12];
    const float* gW    = (const float*)d_in[13];
    const float* gb    = (const float*)d_in[14];
    const float* lW    = (const float*)d_in[15];
    const float* lb    = (const float*)d_in[16];
    const float* dW    = (const float*)d_in[17];
    const float* db    = (const float*)d_in[18];

    const int N = in_sizes[0] / 3;
    const int E = in_sizes[1] / 2;
    const int G = 32;
    const int SZ = DP * DP;
    (void)ws_size; (void)n_in; (void)out_size;

    char* wsb = (char*)d_ws;
    size_t offb = 0;
    auto alloc = [&](size_t bytes) {
        void* p = wsb + offb;
        offb += (bytes + 255) & ~(size_t)255;
        return p;
    };
    ushort_t* hbuf = (ushort_t*)alloc((size_t)N * DP * 2);
    ushort_t* ubuf = (ushort_t*)alloc((size_t)N * DP * 2);
    ushort_t* agg  = (ushort_t*)alloc((size_t)N * DP * 2);
    ushort_t* tbuf = (ushort_t*)alloc((size_t)N * DP * 2);
    ushort_t* h2 = agg;   // alias: h2 dead once first segmax writes agg
    ushort_t* h1 = tbuf;  // alias: h1 dead once g-GEMM writes tbuf
    ushort_t* WU   = (ushort_t*)alloc((size_t)3 * SZ * 2);
    ushort_t* WG   = (ushort_t*)alloc((size_t)3 * SZ * 2);
    ushort_t* Bt01 = (ushort_t*)alloc((size_t)640 * 128 * 2);
    ushort_t* Bt12 = (ushort_t*)alloc((size_t)640 * DP * 2);
    ushort_t* Bt23 = (ushort_t*)alloc((size_t)640 * DP * 2);
    ushort_t* WL3  = (ushort_t*)alloc((size_t)SZ * 2);
    ushort_t* LWa0 = (ushort_t*)alloc((size_t)SZ * 2);
    ushort_t* LWa1 = (ushort_t*)alloc((size_t)SZ * 2);
    ushort_t* pW3a = (ushort_t*)alloc((size_t)128 * DP * 2);
    ushort_t* W2   = (ushort_t*)alloc((size_t)128 * 64 * 2);
    float* bG   = (float*)alloc((size_t)3 * DP * 4);
    float* bL3  = (float*)alloc((size_t)DP * 4);
    float* bC01 = (float*)alloc((size_t)640 * 4);
    float* bC12 = (float*)alloc((size_t)640 * 4);
    float* bC23 = (float*)alloc((size_t)640 * 4);
    int* cnt    = (int*)alloc((size_t)(N + 1) * 4);
    int* offp   = (int*)alloc((size_t)(N + 1) * 4);
    int* cursor = (int*)alloc((size_t)N * 4);
    int* bsum   = (int*)alloc((size_t)256 * 4);
    int* csr    = (int*)alloc((size_t)E * 4);
    float* sums = (float*)alloc((size_t)(G * DD + G) * 4);
    float* cnts = sums + G * DD;

    const int* srcp = ei;
    const int* dstp = ei + E;
    const int nb = (N + 255) / 256;
    const dim3 blk(256);
    const int rowBlocks = (N + 127) / 128;

    // ---- prep (all weight conversions, one launch) ----
    // work items: 11*SZ (WU,WG,Bt12,Bt23,WL3,LWa0,LWa1) + pW3a + Bt01 + W2 + bG + bL3
    const int prepTotal = 11 * SZ + 2 * 128 * DP + 128 * 64 + 3 * DP + DP;
    prep<<<dim3((prepTotal + 255) / 256), blk, 0, stream>>>(
        pW2, pW3, hW, fW, gW, gb, lW, lb,
        WU, WG, Bt12, Bt23, WL3, LWa0, LWa1, pW3a, Bt01, W2, bG, bL3);

    // ---- combined boundary biases ----
    biascomb<<<dim3((3 * 640 + 255) / 256), blk, 0, stream>>>(pb3, lb, hb, WU, bC01, bC12, bC23);

    // ---- weight-combine GEMMs: P = prevW @ WU_next (TRANSC into Bt high halves) ----
    gemm_mfma<5, 0, 0, 0, 0, 0, 1><<<dim3(2, 1), dim3(512), 0, stream>>>(
        pW3a, DP, 128, DP, WU, nullptr, nullptr, nullptr, nullptr, DD,
        Bt01 + (size_t)DP * 128, nullptr, 128);
    gemm_mfma<5, 0, 0, 0, 0, 0, 1><<<dim3(2, 3), dim3(512), 0, stream>>>(
        LWa0, DP, DP, DP, WU + SZ, nullptr, nullptr, nullptr, nullptr, DD,
        Bt12 + (size_t)DP * DP, nullptr, DP);
    gemm_mfma<5, 0, 0, 0, 0, 0, 1><<<dim3(2, 3), dim3(512), 0, stream>>>(
        LWa1, DP, DP, DP, WU + 2 * SZ, nullptr, nullptr, nullptr, nullptr, DD,
        Bt23 + (size_t)DP * DP, nullptr, DP);

    // ---- CSR build ----
    hipMemsetAsync(cnt, 0, (size_t)(N + 1) * 4, stream);
    hist_kernel<<<dim3((E + 255) / 256), blk, 0, stream>>>(dstp, cnt, E);
    scan1<<<dim3(nb), blk, 0, stream>>>(cnt, bsum, N);
    scan2<<<dim3(1), blk, 0, stream>>>(bsum, nb);
    scan3<<<dim3(nb), blk, 0, stream>>>(cnt, bsum, offp, cursor, N);
    scatter_kernel<<<dim3((E + 255) / 256), blk, 0, stream>>>(srcp, dstp, cursor, csr, E);

    // ---- embed MLP ----
    embed1<<<dim3((N * 64 + 255) / 256), blk, 0, stream>>>(x, pW1, pb1, h1, N);
    gemm_mfma<4, 1, 1, 0, 0, 0, 0><<<dim3(1, rowBlocks), dim3(512), 0, stream>>>(
        h1, 64, N, 64, W2, pb2, nullptr, nullptr, nullptr, 128, h2, nullptr, 128);

    // ---- combined embed3 + u1: [h | u1] = h2 @ Bt01 ----
    gemm_mfma<5, 1, 0, 0, 1, DP, 0><<<dim3(4, rowBlocks), dim3(512), 0, stream>>>(
        h2, 128, N, 128, Bt01, bC01, nullptr, x, fW, DD, hbuf, ubuf, DP);

    // ---- 3 PointGNNConv layers ----
    for (int i = 0; i < 3; ++i) {
        const float* fWi = fW + (size_t)i * 90900;
        const float* fbi = fb + (size_t)i * DD;

        // agg = segment_max(u[src], dst) + fb + (delta-pos)@fWp
        segmax<<<dim3((N + 3) / 4), blk, 0, stream>>>(ubuf, offp, csr, x, fWi, fbi, agg, N);

        // t = relu(agg @ gW + gb + h)
        gemm_mfma<5, 1, 1, 1, 0, 0, 0><<<dim3(2, rowBlocks), dim3(512), 0, stream>>>(
            agg, DP, N, DP, WG + (size_t)i * SZ, bG + (size_t)i * DP,
            hbuf, nullptr, nullptr, DD, tbuf, nullptr, DP);

        if (i < 2) {
            // [h_next | u_next] = t @ [lW | lW@WU_next]
            gemm_mfma<5, 1, 0, 0, 1, DP, 0><<<dim3(4, rowBlocks), dim3(512), 0, stream>>>(
                tbuf, DP, N, DP, (i == 0 ? Bt12 : Bt23), (i == 0 ? bC12 : bC23),
                nullptr, x, fW + (size_t)(i + 1) * 90900, DD, hbuf, ubuf, DP);
        } else {
            // h_final = t @ lW3 + lb3
            gemm_mfma<5, 1, 0, 0, 0, 0, 0><<<dim3(2, rowBlocks), dim3(512), 0, stream>>>(
                tbuf, DP, N, DP, WL3, bL3, nullptr, nullptr, nullptr, DD, hbuf, nullptr, DP);
        }
    }

    // ---- global mean pool + head ----
    hipMemsetAsync(sums, 0, (size_t)(G * DD + G) * 4, stream);
    pool_kernel<<<dim3((N + 127) / 128), dim3(320), 0, stream>>>(hbuf, batch, sums, cnts, N, 128);
    head_kernel<<<dim3(1), dim3(256), 0, stream>>>(sums, cnts, dW, db, (float*)d_out);
}